// Round 1
// baseline (1127.330 us; speedup 1.0000x reference)
//
#include <hip/hip_runtime.h>

// ===================== graph preprocessing =====================

__global__ void k_deg(const int* __restrict__ dst, int E, int* __restrict__ deg) {
    int i = blockIdx.x * blockDim.x + threadIdx.x;
    if (i < E) atomicAdd(&deg[dst[i]], 1);
}

__global__ void k_dinv(const int* __restrict__ deg, int N, float* __restrict__ dinv) {
    int i = blockIdx.x * blockDim.x + threadIdx.x;
    if (i < N) dinv[i] = 1.0f / sqrtf((float)(deg[i] + 1));  // +1 = self-loop
}

// 3-kernel exclusive scan over deg -> rowptr (N up to 256*256)
__global__ void k_scan1(const int* __restrict__ deg, int N, int* __restrict__ part, int* __restrict__ bsum) {
    __shared__ int s[256];
    int i = blockIdx.x * 256 + threadIdx.x;
    int v = (i < N) ? deg[i] : 0;
    s[threadIdx.x] = v;
    __syncthreads();
    for (int off = 1; off < 256; off <<= 1) {
        int t = (threadIdx.x >= off) ? s[threadIdx.x - off] : 0;
        __syncthreads();
        s[threadIdx.x] += t;
        __syncthreads();
    }
    if (i < N) part[i] = s[threadIdx.x] - v;  // exclusive within block
    if (threadIdx.x == 255) bsum[blockIdx.x] = s[255];
}

__global__ void k_scan2(int* __restrict__ bsum, int nb) {
    __shared__ int s[256];
    int v = (threadIdx.x < nb) ? bsum[threadIdx.x] : 0;
    s[threadIdx.x] = v;
    __syncthreads();
    for (int off = 1; off < 256; off <<= 1) {
        int t = (threadIdx.x >= off) ? s[threadIdx.x - off] : 0;
        __syncthreads();
        s[threadIdx.x] += t;
        __syncthreads();
    }
    if (threadIdx.x < nb) bsum[threadIdx.x] = s[threadIdx.x] - v;  // exclusive
}

__global__ void k_scan3(const int* __restrict__ part, const int* __restrict__ bsum, int N, int E,
                        int* __restrict__ rowptr, int* __restrict__ cursor) {
    int i = blockIdx.x * 256 + threadIdx.x;
    if (i < N) {
        int v = part[i] + bsum[blockIdx.x];
        rowptr[i] = v;
        cursor[i] = v;
    }
    if (i == 0) rowptr[N] = E;
}

__global__ void k_fill(const int* __restrict__ src, const int* __restrict__ dst, int E,
                       const float* __restrict__ dinv, int* __restrict__ cursor,
                       int* __restrict__ col, float* __restrict__ nrm) {
    int e = blockIdx.x * blockDim.x + threadIdx.x;
    if (e < E) {
        int s = src[e], d = dst[e];
        int p = atomicAdd(&cursor[d], 1);
        col[p] = s;
        nrm[p] = dinv[s] * dinv[d];
    }
}

__global__ void k_cnt(const int* __restrict__ batch, int N, int* __restrict__ cnt) {
    int i = blockIdx.x * blockDim.x + threadIdx.x;
    if (i < N) atomicAdd(&cnt[batch[i]], 1);
}

// ===================== fp32 tiled GEMM: C[N x M] = A[N x K] @ B[K x M] =====================
// BM=BN=128, BK=16, 256 threads, 8x8 outputs/thread. M must be multiple of 128, K of 16.

#define BM 128
#define BN 128
#define BK 16

__global__ __launch_bounds__(256) void k_gemm(const float* __restrict__ A, const float* __restrict__ B,
                                              float* __restrict__ C, int Nrows, int K, int M) {
    __shared__ float As[BK][BM];
    __shared__ float Bs[BK][BN];
    const int tid = threadIdx.x;
    const int tx = tid & 15, ty = tid >> 4;
    const int row0 = blockIdx.y * BM;
    const int col0 = blockIdx.x * BN;

    float acc[8][8] = {{0.f}};

    for (int k0 = 0; k0 < K; k0 += BK) {
        // stage A tile (transposed into As[k][m])
#pragma unroll
        for (int p = 0; p < 2; ++p) {
            int i = tid + p * 256;          // 512 float4s = 128 rows x 4
            int r = i >> 2, c4 = i & 3;
            float4 v = make_float4(0.f, 0.f, 0.f, 0.f);
            if (row0 + r < Nrows) v = *(const float4*)&A[(size_t)(row0 + r) * K + k0 + c4 * 4];
            As[c4 * 4 + 0][r] = v.x;
            As[c4 * 4 + 1][r] = v.y;
            As[c4 * 4 + 2][r] = v.z;
            As[c4 * 4 + 3][r] = v.w;
        }
        // stage B tile
#pragma unroll
        for (int p = 0; p < 2; ++p) {
            int i = tid + p * 256;          // 512 float4s = 16 rows x 32
            int kk = i >> 5, n4 = i & 31;
            float4 v = *(const float4*)&B[(size_t)(k0 + kk) * M + col0 + n4 * 4];
            *(float4*)&Bs[kk][n4 * 4] = v;
        }
        __syncthreads();

#pragma unroll
        for (int k = 0; k < BK; ++k) {
            float a[8], b[8];
            *(float4*)&a[0] = *(const float4*)&As[k][ty * 8];
            *(float4*)&a[4] = *(const float4*)&As[k][ty * 8 + 4];
            *(float4*)&b[0] = *(const float4*)&Bs[k][tx * 8];
            *(float4*)&b[4] = *(const float4*)&Bs[k][tx * 8 + 4];
#pragma unroll
            for (int i = 0; i < 8; ++i)
#pragma unroll
                for (int j = 0; j < 8; ++j)
                    acc[i][j] += a[i] * b[j];
        }
        __syncthreads();
    }

#pragma unroll
    for (int i = 0; i < 8; ++i) {
        int r = row0 + ty * 8 + i;
        if (r < Nrows) {
            *(float4*)&C[(size_t)r * M + col0 + tx * 8] =
                make_float4(acc[i][0], acc[i][1], acc[i][2], acc[i][3]);
            *(float4*)&C[(size_t)r * M + col0 + tx * 8 + 4] =
                make_float4(acc[i][4], acc[i][5], acc[i][6], acc[i][7]);
        }
    }
}

// ===================== aggregation: out[v] = relu(b + dinv2[v]*H[v] + sum_e nrm*H[col]) =====================
// one wave per node, lane l owns float4 features [4l, 4l+4). D fixed = 256.

__global__ __launch_bounds__(256) void k_agg(const float* __restrict__ H, const int* __restrict__ rowptr,
                                             const int* __restrict__ col, const float* __restrict__ nrm,
                                             const float* __restrict__ dinv, const float* __restrict__ bias,
                                             float* __restrict__ out, int N) {
    const int wave = threadIdx.x >> 6, lane = threadIdx.x & 63;
    const int v = blockIdx.x * 4 + wave;
    if (v >= N) return;

    const float di = dinv[v];
    const float selfn = di * di;
    float4 h = ((const float4*)&H[(size_t)v * 256])[lane];
    float ax = selfn * h.x, ay = selfn * h.y, az = selfn * h.z, aw = selfn * h.w;

    int e = rowptr[v];
    const int end = rowptr[v + 1];
    for (; e < end; ++e) {
        int u = col[e];
        float w = nrm[e];
        float4 hu = ((const float4*)&H[(size_t)u * 256])[lane];
        ax += w * hu.x;
        ay += w * hu.y;
        az += w * hu.z;
        aw += w * hu.w;
    }

    float4 b = ((const float4*)bias)[lane];
    float4 o;
    o.x = fmaxf(ax + b.x, 0.f);
    o.y = fmaxf(ay + b.y, 0.f);
    o.z = fmaxf(az + b.z, 0.f);
    o.w = fmaxf(aw + b.w, 0.f);
    ((float4*)&out[(size_t)v * 256])[lane] = o;
}

// ===================== mean pool (batch sorted) =====================

__global__ __launch_bounds__(256) void k_pool(const float* __restrict__ H, const int* __restrict__ cnt,
                                              float* __restrict__ g) {
    const int gid = blockIdx.x, t = threadIdx.x;
    __shared__ int s_start, s_cnt;
    if (t == 0) {
        int s = 0;
        for (int i = 0; i < gid; ++i) s += cnt[i];
        s_start = s;
        s_cnt = cnt[gid];
    }
    __syncthreads();
    const int start = s_start, c = s_cnt;
    float acc = 0.f;
    for (int n = 0; n < c; ++n) acc += H[(size_t)(start + n) * 256 + t];
    g[gid * 256 + t] = acc / fmaxf((float)c, 1.0f);
}

// ===================== classifier head =====================

__global__ __launch_bounds__(256) void k_cls(const float* __restrict__ g, const float* __restrict__ Wc1,
                                             const float* __restrict__ bc1, const float* __restrict__ Wc2,
                                             const float* __restrict__ bc2, float* __restrict__ out) {
    __shared__ float sg[256], sh[256];
    const int b = blockIdx.x, t = threadIdx.x;
    sg[t] = g[b * 256 + t];
    __syncthreads();
    float acc = bc1[t];
    for (int k = 0; k < 256; ++k) acc += sg[k] * Wc1[k * 256 + t];
    sh[t] = fmaxf(acc, 0.f);
    __syncthreads();
    if (t < 5) {
        float o = bc2[t];
        for (int k = 0; k < 256; ++k) o += sh[k] * Wc2[k * 5 + t];
        out[b * 5 + t] = o;
    }
}

// ===================== launch =====================

extern "C" void kernel_launch(void* const* d_in, const int* in_sizes, int n_in,
                              void* d_out, int out_size, void* d_ws, size_t ws_size,
                              hipStream_t stream) {
    const float* x    = (const float*)d_in[0];
    const int*   eidx = (const int*)d_in[1];
    const int*   batch= (const int*)d_in[2];
    const float* W0 = (const float*)d_in[3];  const float* b0 = (const float*)d_in[4];
    const float* W1 = (const float*)d_in[5];  const float* b1 = (const float*)d_in[6];
    const float* W2 = (const float*)d_in[7];  const float* b2 = (const float*)d_in[8];
    const float* Wc1= (const float*)d_in[9];  const float* bc1= (const float*)d_in[10];
    const float* Wc2= (const float*)d_in[11]; const float* bc2= (const float*)d_in[12];
    float* out = (float*)d_out;

    const int N   = in_sizes[2];       // 50000
    const int E   = in_sizes[1] / 2;   // 500000
    const int DIN = in_sizes[0] / N;   // 128
    const int DH  = in_sizes[4];       // 256
    const int* src = eidx;
    const int* dst = eidx + E;

    // workspace carve (256B aligned)
    char* p = (char*)d_ws;
    auto alloc = [&](size_t bytes) {
        char* r = p;
        p += (bytes + 255) & ~(size_t)255;
        return (void*)r;
    };
    float* buf1  = (float*)alloc((size_t)N * DH * 4);
    float* buf2  = (float*)alloc((size_t)N * DH * 4);
    int*   deg   = (int*)alloc((size_t)N * 4);
    float* dinv  = (float*)alloc((size_t)N * 4);
    int*   part  = (int*)alloc((size_t)N * 4);
    int*   bsum  = (int*)alloc(256 * 4);
    int*   rowptr= (int*)alloc((size_t)(N + 1) * 4);
    int*   cursor= (int*)alloc((size_t)N * 4);
    int*   col   = (int*)alloc((size_t)E * 4);
    float* nrm   = (float*)alloc((size_t)E * 4);
    int*   gcnt  = (int*)alloc(64 * 4);
    float* gpool = (float*)alloc(64 * (size_t)DH * 4);

    hipMemsetAsync(deg, 0, (size_t)N * 4, stream);
    hipMemsetAsync(gcnt, 0, 64 * 4, stream);

    const int nb = (N + 255) / 256;
    k_deg <<<(E + 255) / 256, 256, 0, stream>>>(dst, E, deg);
    k_dinv<<<nb, 256, 0, stream>>>(deg, N, dinv);
    k_scan1<<<nb, 256, 0, stream>>>(deg, N, part, bsum);
    k_scan2<<<1, 256, 0, stream>>>(bsum, nb);
    k_scan3<<<nb, 256, 0, stream>>>(part, bsum, N, E, rowptr, cursor);
    k_fill<<<(E + 255) / 256, 256, 0, stream>>>(src, dst, E, dinv, cursor, col, nrm);
    k_cnt <<<nb, 256, 0, stream>>>(batch, N, gcnt);

    dim3 gemmGrid(DH / BN, (N + BM - 1) / BM);
    const int aggBlocks = (N + 3) / 4;

    // layer 0: 128 -> 256
    k_gemm<<<gemmGrid, 256, 0, stream>>>(x, W0, buf1, N, DIN, DH);
    k_agg <<<aggBlocks, 256, 0, stream>>>(buf1, rowptr, col, nrm, dinv, b0, buf2, N);
    // layer 1: 256 -> 256
    k_gemm<<<gemmGrid, 256, 0, stream>>>(buf2, W1, buf1, N, DH, DH);
    k_agg <<<aggBlocks, 256, 0, stream>>>(buf1, rowptr, col, nrm, dinv, b1, buf2, N);
    // layer 2: 256 -> 256
    k_gemm<<<gemmGrid, 256, 0, stream>>>(buf2, W2, buf1, N, DH, DH);
    k_agg <<<aggBlocks, 256, 0, stream>>>(buf1, rowptr, col, nrm, dinv, b2, buf2, N);

    // pool + head
    k_pool<<<64, 256, 0, stream>>>(buf2, gcnt, gpool);
    k_cls <<<64, 256, 0, stream>>>(gpool, Wc1, bc1, Wc2, bc2, out);
}

// Round 2
// 898.126 us; speedup vs baseline: 1.2552x; 1.2552x over previous
//
#include <hip/hip_runtime.h>

// ===================== graph preprocessing =====================

__global__ void k_deg(const int* __restrict__ dst, int E, int* __restrict__ deg) {
    int i = blockIdx.x * blockDim.x + threadIdx.x;
    if (i < E) atomicAdd(&deg[dst[i]], 1);
}

__global__ void k_dinv(const int* __restrict__ deg, int N, float* __restrict__ dinv) {
    int i = blockIdx.x * blockDim.x + threadIdx.x;
    if (i < N) dinv[i] = 1.0f / sqrtf((float)(deg[i] + 1));  // +1 = self-loop
}

// 3-kernel exclusive scan over deg -> rowptr (N up to 256*256)
__global__ void k_scan1(const int* __restrict__ deg, int N, int* __restrict__ part, int* __restrict__ bsum) {
    __shared__ int s[256];
    int i = blockIdx.x * 256 + threadIdx.x;
    int v = (i < N) ? deg[i] : 0;
    s[threadIdx.x] = v;
    __syncthreads();
    for (int off = 1; off < 256; off <<= 1) {
        int t = (threadIdx.x >= off) ? s[threadIdx.x - off] : 0;
        __syncthreads();
        s[threadIdx.x] += t;
        __syncthreads();
    }
    if (i < N) part[i] = s[threadIdx.x] - v;  // exclusive within block
    if (threadIdx.x == 255) bsum[blockIdx.x] = s[255];
}

__global__ void k_scan2(int* __restrict__ bsum, int nb) {
    __shared__ int s[256];
    int v = (threadIdx.x < nb) ? bsum[threadIdx.x] : 0;
    s[threadIdx.x] = v;
    __syncthreads();
    for (int off = 1; off < 256; off <<= 1) {
        int t = (threadIdx.x >= off) ? s[threadIdx.x - off] : 0;
        __syncthreads();
        s[threadIdx.x] += t;
        __syncthreads();
    }
    if (threadIdx.x < nb) bsum[threadIdx.x] = s[threadIdx.x] - v;  // exclusive
}

__global__ void k_scan3(const int* __restrict__ part, const int* __restrict__ bsum, int N, int E,
                        int* __restrict__ rowptr, int* __restrict__ cursor) {
    int i = blockIdx.x * 256 + threadIdx.x;
    if (i < N) {
        int v = part[i] + bsum[blockIdx.x];
        rowptr[i] = v;
        cursor[i] = v;
    }
    if (i == 0) rowptr[N] = E;
}

__global__ void k_fill(const int* __restrict__ src, const int* __restrict__ dst, int E,
                       const float* __restrict__ dinv, int* __restrict__ cursor,
                       int* __restrict__ col, float* __restrict__ nrm) {
    int e = blockIdx.x * blockDim.x + threadIdx.x;
    if (e < E) {
        int s = src[e], d = dst[e];
        int p = atomicAdd(&cursor[d], 1);
        col[p] = s;
        nrm[p] = dinv[s] * dinv[d];
    }
}

// graph boundaries via binary search over the SORTED batch array.
// gstart[g] = first index i with batch[i] >= g; gstart[64] = N.
// Replaces the 235us atomic histogram (sorted batch => same-address atomic serialization).
__global__ void k_gbounds(const int* __restrict__ batch, int N, int ngraphs, int* __restrict__ gstart) {
    int g = threadIdx.x;
    if (g > ngraphs) return;
    if (g == ngraphs) { gstart[g] = N; return; }
    int lo = 0, hi = N;  // find lower_bound(batch, g)
    while (lo < hi) {
        int mid = (lo + hi) >> 1;
        if (batch[mid] < g) lo = mid + 1; else hi = mid;
    }
    gstart[g] = lo;
}

// ===================== fp32 tiled GEMM: C[N x M] = A[N x K] @ B[K x M] =====================
// BM=BN=128, BK=16, 256 threads, 8x8 outputs/thread. M must be multiple of 128, K of 16.

#define BM 128
#define BN 128
#define BK 16

__global__ __launch_bounds__(256) void k_gemm(const float* __restrict__ A, const float* __restrict__ B,
                                              float* __restrict__ C, int Nrows, int K, int M) {
    __shared__ float As[BK][BM];
    __shared__ float Bs[BK][BN];
    const int tid = threadIdx.x;
    const int tx = tid & 15, ty = tid >> 4;
    const int row0 = blockIdx.y * BM;
    const int col0 = blockIdx.x * BN;

    float acc[8][8] = {{0.f}};

    for (int k0 = 0; k0 < K; k0 += BK) {
        // stage A tile (transposed into As[k][m])
#pragma unroll
        for (int p = 0; p < 2; ++p) {
            int i = tid + p * 256;          // 512 float4s = 128 rows x 4
            int r = i >> 2, c4 = i & 3;
            float4 v = make_float4(0.f, 0.f, 0.f, 0.f);
            if (row0 + r < Nrows) v = *(const float4*)&A[(size_t)(row0 + r) * K + k0 + c4 * 4];
            As[c4 * 4 + 0][r] = v.x;
            As[c4 * 4 + 1][r] = v.y;
            As[c4 * 4 + 2][r] = v.z;
            As[c4 * 4 + 3][r] = v.w;
        }
        // stage B tile
#pragma unroll
        for (int p = 0; p < 2; ++p) {
            int i = tid + p * 256;          // 512 float4s = 16 rows x 32
            int kk = i >> 5, n4 = i & 31;
            float4 v = *(const float4*)&B[(size_t)(k0 + kk) * M + col0 + n4 * 4];
            *(float4*)&Bs[kk][n4 * 4] = v;
        }
        __syncthreads();

#pragma unroll
        for (int k = 0; k < BK; ++k) {
            float a[8], b[8];
            *(float4*)&a[0] = *(const float4*)&As[k][ty * 8];
            *(float4*)&a[4] = *(const float4*)&As[k][ty * 8 + 4];
            *(float4*)&b[0] = *(const float4*)&Bs[k][tx * 8];
            *(float4*)&b[4] = *(const float4*)&Bs[k][tx * 8 + 4];
#pragma unroll
            for (int i = 0; i < 8; ++i)
#pragma unroll
                for (int j = 0; j < 8; ++j)
                    acc[i][j] += a[i] * b[j];
        }
        __syncthreads();
    }

#pragma unroll
    for (int i = 0; i < 8; ++i) {
        int r = row0 + ty * 8 + i;
        if (r < Nrows) {
            *(float4*)&C[(size_t)r * M + col0 + tx * 8] =
                make_float4(acc[i][0], acc[i][1], acc[i][2], acc[i][3]);
            *(float4*)&C[(size_t)r * M + col0 + tx * 8 + 4] =
                make_float4(acc[i][4], acc[i][5], acc[i][6], acc[i][7]);
        }
    }
}

// ===================== aggregation: out[v] = relu(b + dinv2[v]*H[v] + sum_e nrm*H[col]) =====================
// one wave per node, lane l owns float4 features [4l, 4l+4). D fixed = 256.

__global__ __launch_bounds__(256) void k_agg(const float* __restrict__ H, const int* __restrict__ rowptr,
                                             const int* __restrict__ col, const float* __restrict__ nrm,
                                             const float* __restrict__ dinv, const float* __restrict__ bias,
                                             float* __restrict__ out, int N) {
    const int wave = threadIdx.x >> 6, lane = threadIdx.x & 63;
    const int v = blockIdx.x * 4 + wave;
    if (v >= N) return;

    const float di = dinv[v];
    const float selfn = di * di;
    float4 h = ((const float4*)&H[(size_t)v * 256])[lane];
    float ax = selfn * h.x, ay = selfn * h.y, az = selfn * h.z, aw = selfn * h.w;

    int e = rowptr[v];
    const int end = rowptr[v + 1];
    for (; e < end; ++e) {
        int u = col[e];
        float w = nrm[e];
        float4 hu = ((const float4*)&H[(size_t)u * 256])[lane];
        ax += w * hu.x;
        ay += w * hu.y;
        az += w * hu.z;
        aw += w * hu.w;
    }

    float4 b = ((const float4*)bias)[lane];
    float4 o;
    o.x = fmaxf(ax + b.x, 0.f);
    o.y = fmaxf(ay + b.y, 0.f);
    o.z = fmaxf(az + b.z, 0.f);
    o.w = fmaxf(aw + b.w, 0.f);
    ((float4*)&out[(size_t)v * 256])[lane] = o;
}

// ===================== mean pool (batch sorted; gstart from binary search) =====================

__global__ __launch_bounds__(256) void k_pool(const float* __restrict__ H, const int* __restrict__ gstart,
                                              float* __restrict__ g) {
    const int gid = blockIdx.x, t = threadIdx.x;
    const int start = gstart[gid];
    const int c = gstart[gid + 1] - start;
    float acc = 0.f;
    for (int n = 0; n < c; ++n) acc += H[(size_t)(start + n) * 256 + t];
    g[gid * 256 + t] = acc / fmaxf((float)c, 1.0f);
}

// ===================== classifier head =====================

__global__ __launch_bounds__(256) void k_cls(const float* __restrict__ g, const float* __restrict__ Wc1,
                                             const float* __restrict__ bc1, const float* __restrict__ Wc2,
                                             const float* __restrict__ bc2, float* __restrict__ out) {
    __shared__ float sg[256], sh[256];
    const int b = blockIdx.x, t = threadIdx.x;
    sg[t] = g[b * 256 + t];
    __syncthreads();
    float acc = bc1[t];
    for (int k = 0; k < 256; ++k) acc += sg[k] * Wc1[k * 256 + t];
    sh[t] = fmaxf(acc, 0.f);
    __syncthreads();
    if (t < 5) {
        float o = bc2[t];
        for (int k = 0; k < 256; ++k) o += sh[k] * Wc2[k * 5 + t];
        out[b * 5 + t] = o;
    }
}

// ===================== launch =====================

extern "C" void kernel_launch(void* const* d_in, const int* in_sizes, int n_in,
                              void* d_out, int out_size, void* d_ws, size_t ws_size,
                              hipStream_t stream) {
    const float* x    = (const float*)d_in[0];
    const int*   eidx = (const int*)d_in[1];
    const int*   batch= (const int*)d_in[2];
    const float* W0 = (const float*)d_in[3];  const float* b0 = (const float*)d_in[4];
    const float* W1 = (const float*)d_in[5];  const float* b1 = (const float*)d_in[6];
    const float* W2 = (const float*)d_in[7];  const float* b2 = (const float*)d_in[8];
    const float* Wc1= (const float*)d_in[9];  const float* bc1= (const float*)d_in[10];
    const float* Wc2= (const float*)d_in[11]; const float* bc2= (const float*)d_in[12];
    float* out = (float*)d_out;

    const int N   = in_sizes[2];       // 50000
    const int E   = in_sizes[1] / 2;   // 500000
    const int DIN = in_sizes[0] / N;   // 128
    const int DH  = in_sizes[4];       // 256
    const int* src = eidx;
    const int* dst = eidx + E;

    // workspace carve (256B aligned)
    char* p = (char*)d_ws;
    auto alloc = [&](size_t bytes) {
        char* r = p;
        p += (bytes + 255) & ~(size_t)255;
        return (void*)r;
    };
    float* buf1  = (float*)alloc((size_t)N * DH * 4);
    float* buf2  = (float*)alloc((size_t)N * DH * 4);
    int*   deg   = (int*)alloc((size_t)N * 4);
    float* dinv  = (float*)alloc((size_t)N * 4);
    int*   part  = (int*)alloc((size_t)N * 4);
    int*   bsum  = (int*)alloc(256 * 4);
    int*   rowptr= (int*)alloc((size_t)(N + 1) * 4);
    int*   cursor= (int*)alloc((size_t)N * 4);
    int*   col   = (int*)alloc((size_t)E * 4);
    float* nrm   = (float*)alloc((size_t)E * 4);
    int*   gstart= (int*)alloc(65 * 4);
    float* gpool = (float*)alloc(64 * (size_t)DH * 4);

    hipMemsetAsync(deg, 0, (size_t)N * 4, stream);

    const int nb = (N + 255) / 256;
    k_deg <<<(E + 255) / 256, 256, 0, stream>>>(dst, E, deg);
    k_dinv<<<nb, 256, 0, stream>>>(deg, N, dinv);
    k_scan1<<<nb, 256, 0, stream>>>(deg, N, part, bsum);
    k_scan2<<<1, 256, 0, stream>>>(bsum, nb);
    k_scan3<<<nb, 256, 0, stream>>>(part, bsum, N, E, rowptr, cursor);
    k_fill<<<(E + 255) / 256, 256, 0, stream>>>(src, dst, E, dinv, cursor, col, nrm);
    k_gbounds<<<1, 128, 0, stream>>>(batch, N, 64, gstart);

    dim3 gemmGrid(DH / BN, (N + BM - 1) / BM);
    const int aggBlocks = (N + 3) / 4;

    // layer 0: 128 -> 256
    k_gemm<<<gemmGrid, 256, 0, stream>>>(x, W0, buf1, N, DIN, DH);
    k_agg <<<aggBlocks, 256, 0, stream>>>(buf1, rowptr, col, nrm, dinv, b0, buf2, N);
    // layer 1: 256 -> 256
    k_gemm<<<gemmGrid, 256, 0, stream>>>(buf2, W1, buf1, N, DH, DH);
    k_agg <<<aggBlocks, 256, 0, stream>>>(buf1, rowptr, col, nrm, dinv, b1, buf2, N);
    // layer 2: 256 -> 256
    k_gemm<<<gemmGrid, 256, 0, stream>>>(buf2, W2, buf1, N, DH, DH);
    k_agg <<<aggBlocks, 256, 0, stream>>>(buf1, rowptr, col, nrm, dinv, b2, buf2, N);

    // pool + head
    k_pool<<<64, 256, 0, stream>>>(buf2, gstart, gpool);
    k_cls <<<64, 256, 0, stream>>>(gpool, Wc1, bc1, Wc2, bc2, out);
}

// Round 3
// 703.649 us; speedup vs baseline: 1.6021x; 1.2764x over previous
//
#include <hip/hip_runtime.h>

// ===================== graph preprocessing =====================

__global__ void k_deg(const int* __restrict__ dst, int E, int* __restrict__ deg) {
    int i = blockIdx.x * blockDim.x + threadIdx.x;
    if (i < E) atomicAdd(&deg[dst[i]], 1);
}

__global__ void k_dinv(const int* __restrict__ deg, int N, float* __restrict__ dinv) {
    int i = blockIdx.x * blockDim.x + threadIdx.x;
    if (i < N) dinv[i] = 1.0f / sqrtf((float)(deg[i] + 1));  // +1 = self-loop
}

// 3-kernel exclusive scan over deg -> rowptr (N up to 256*256)
__global__ void k_scan1(const int* __restrict__ deg, int N, int* __restrict__ part, int* __restrict__ bsum) {
    __shared__ int s[256];
    int i = blockIdx.x * 256 + threadIdx.x;
    int v = (i < N) ? deg[i] : 0;
    s[threadIdx.x] = v;
    __syncthreads();
    for (int off = 1; off < 256; off <<= 1) {
        int t = (threadIdx.x >= off) ? s[threadIdx.x - off] : 0;
        __syncthreads();
        s[threadIdx.x] += t;
        __syncthreads();
    }
    if (i < N) part[i] = s[threadIdx.x] - v;  // exclusive within block
    if (threadIdx.x == 255) bsum[blockIdx.x] = s[255];
}

__global__ void k_scan2(int* __restrict__ bsum, int nb) {
    __shared__ int s[256];
    int v = (threadIdx.x < nb) ? bsum[threadIdx.x] : 0;
    s[threadIdx.x] = v;
    __syncthreads();
    for (int off = 1; off < 256; off <<= 1) {
        int t = (threadIdx.x >= off) ? s[threadIdx.x - off] : 0;
        __syncthreads();
        s[threadIdx.x] += t;
        __syncthreads();
    }
    if (threadIdx.x < nb) bsum[threadIdx.x] = s[threadIdx.x] - v;  // exclusive
}

__global__ void k_scan3(const int* __restrict__ part, const int* __restrict__ bsum, int N, int E,
                        int* __restrict__ rowptr, int* __restrict__ cursor) {
    int i = blockIdx.x * 256 + threadIdx.x;
    if (i < N) {
        int v = part[i] + bsum[blockIdx.x];
        rowptr[i] = v;
        cursor[i] = v;
    }
    if (i == 0) rowptr[N] = E;
}

__global__ void k_fill(const int* __restrict__ src, const int* __restrict__ dst, int E,
                       const float* __restrict__ dinv, int* __restrict__ cursor,
                       int* __restrict__ col, float* __restrict__ nrm) {
    int e = blockIdx.x * blockDim.x + threadIdx.x;
    if (e < E) {
        int s = src[e], d = dst[e];
        int p = atomicAdd(&cursor[d], 1);
        col[p] = s;
        nrm[p] = dinv[s] * dinv[d];
    }
}

// graph boundaries via binary search over the SORTED batch array.
__global__ void k_gbounds(const int* __restrict__ batch, int N, int ngraphs, int* __restrict__ gstart) {
    int g = threadIdx.x;
    if (g > ngraphs) return;
    if (g == ngraphs) { gstart[g] = N; return; }
    int lo = 0, hi = N;  // lower_bound(batch, g)
    while (lo < hi) {
        int mid = (lo + hi) >> 1;
        if (batch[mid] < g) lo = mid + 1; else hi = mid;
    }
    gstart[g] = lo;
}

// ===================== fp32 tiled GEMM: C[N x M] = A[N x K] @ B[K x M] =====================
// BM=BN=128, BK=16, 256 threads, 8x8 outputs/thread. M must be multiple of 128, K of 16.

#define BM 128
#define BN 128
#define BK 16

__global__ __launch_bounds__(256) void k_gemm(const float* __restrict__ A, const float* __restrict__ B,
                                              float* __restrict__ C, int Nrows, int K, int M) {
    __shared__ float As[BK][BM];
    __shared__ float Bs[BK][BN];
    const int tid = threadIdx.x;
    const int tx = tid & 15, ty = tid >> 4;
    const int row0 = blockIdx.y * BM;
    const int col0 = blockIdx.x * BN;

    float acc[8][8] = {{0.f}};

    for (int k0 = 0; k0 < K; k0 += BK) {
#pragma unroll
        for (int p = 0; p < 2; ++p) {
            int i = tid + p * 256;
            int r = i >> 2, c4 = i & 3;
            float4 v = make_float4(0.f, 0.f, 0.f, 0.f);
            if (row0 + r < Nrows) v = *(const float4*)&A[(size_t)(row0 + r) * K + k0 + c4 * 4];
            As[c4 * 4 + 0][r] = v.x;
            As[c4 * 4 + 1][r] = v.y;
            As[c4 * 4 + 2][r] = v.z;
            As[c4 * 4 + 3][r] = v.w;
        }
#pragma unroll
        for (int p = 0; p < 2; ++p) {
            int i = tid + p * 256;
            int kk = i >> 5, n4 = i & 31;
            float4 v = *(const float4*)&B[(size_t)(k0 + kk) * M + col0 + n4 * 4];
            *(float4*)&Bs[kk][n4 * 4] = v;
        }
        __syncthreads();

#pragma unroll
        for (int k = 0; k < BK; ++k) {
            float a[8], b[8];
            *(float4*)&a[0] = *(const float4*)&As[k][ty * 8];
            *(float4*)&a[4] = *(const float4*)&As[k][ty * 8 + 4];
            *(float4*)&b[0] = *(const float4*)&Bs[k][tx * 8];
            *(float4*)&b[4] = *(const float4*)&Bs[k][tx * 8 + 4];
#pragma unroll
            for (int i = 0; i < 8; ++i)
#pragma unroll
                for (int j = 0; j < 8; ++j)
                    acc[i][j] += a[i] * b[j];
        }
        __syncthreads();
    }

#pragma unroll
    for (int i = 0; i < 8; ++i) {
        int r = row0 + ty * 8 + i;
        if (r < Nrows) {
            *(float4*)&C[(size_t)r * M + col0 + tx * 8] =
                make_float4(acc[i][0], acc[i][1], acc[i][2], acc[i][3]);
            *(float4*)&C[(size_t)r * M + col0 + tx * 8 + 4] =
                make_float4(acc[i][4], acc[i][5], acc[i][6], acc[i][7]);
        }
    }
}

// ===================== aggregation: out[v] = relu(b + dinv2[v]*H[v] + sum_e nrm*H[col]) =====================

__global__ __launch_bounds__(256) void k_agg(const float* __restrict__ H, const int* __restrict__ rowptr,
                                             const int* __restrict__ col, const float* __restrict__ nrm,
                                             const float* __restrict__ dinv, const float* __restrict__ bias,
                                             float* __restrict__ out, int N) {
    const int wave = threadIdx.x >> 6, lane = threadIdx.x & 63;
    const int v = blockIdx.x * 4 + wave;
    if (v >= N) return;

    const float di = dinv[v];
    const float selfn = di * di;
    float4 h = ((const float4*)&H[(size_t)v * 256])[lane];
    float ax = selfn * h.x, ay = selfn * h.y, az = selfn * h.z, aw = selfn * h.w;

    int e = rowptr[v];
    const int end = rowptr[v + 1];
    for (; e < end; ++e) {
        int u = col[e];
        float w = nrm[e];
        float4 hu = ((const float4*)&H[(size_t)u * 256])[lane];
        ax += w * hu.x;
        ay += w * hu.y;
        az += w * hu.z;
        aw += w * hu.w;
    }

    float4 b = ((const float4*)bias)[lane];
    float4 o;
    o.x = fmaxf(ax + b.x, 0.f);
    o.y = fmaxf(ay + b.y, 0.f);
    o.z = fmaxf(az + b.z, 0.f);
    o.w = fmaxf(aw + b.w, 0.f);
    ((float4*)&out[(size_t)v * 256])[lane] = o;
}

// ===================== mean pool, two-stage deterministic tree =====================
// stage 1: grid (64 graphs x POOL_S slices), each block sums a contiguous node
// slice of its graph (256 threads = 256 features, coalesced).
#define POOL_S 32

__global__ __launch_bounds__(256) void k_pool1(const float* __restrict__ H, const int* __restrict__ gstart,
                                               float* __restrict__ partial) {
    const int gid = blockIdx.x, slice = blockIdx.y, t = threadIdx.x;
    const int start = gstart[gid], end = gstart[gid + 1];
    const int len = end - start;
    const int chunk = (len + POOL_S - 1) / POOL_S;
    int a = start + slice * chunk;
    int b = a + chunk; if (b > end) b = end;
    float acc = 0.f;
    for (int n = a; n < b; ++n) acc += H[(size_t)n * 256 + t];
    partial[((size_t)gid * POOL_S + slice) * 256 + t] = acc;
}

// stage 2: 64 blocks reduce the POOL_S partials in fixed order, divide by count.
__global__ __launch_bounds__(256) void k_pool2(const float* __restrict__ partial, const int* __restrict__ gstart,
                                               float* __restrict__ g) {
    const int gid = blockIdx.x, t = threadIdx.x;
    float acc = 0.f;
#pragma unroll
    for (int s = 0; s < POOL_S; ++s) acc += partial[((size_t)gid * POOL_S + s) * 256 + t];
    const float c = (float)(gstart[gid + 1] - gstart[gid]);
    g[gid * 256 + t] = acc / fmaxf(c, 1.0f);
}

// ===================== classifier head =====================

__global__ __launch_bounds__(256) void k_cls(const float* __restrict__ g, const float* __restrict__ Wc1,
                                             const float* __restrict__ bc1, const float* __restrict__ Wc2,
                                             const float* __restrict__ bc2, float* __restrict__ out) {
    __shared__ float sg[256], sh[256];
    const int b = blockIdx.x, t = threadIdx.x;
    sg[t] = g[b * 256 + t];
    __syncthreads();
    float acc = bc1[t];
    for (int k = 0; k < 256; ++k) acc += sg[k] * Wc1[k * 256 + t];
    sh[t] = fmaxf(acc, 0.f);
    __syncthreads();
    if (t < 5) {
        float o = bc2[t];
        for (int k = 0; k < 256; ++k) o += sh[k] * Wc2[k * 5 + t];
        out[b * 5 + t] = o;
    }
}

// ===================== launch =====================

extern "C" void kernel_launch(void* const* d_in, const int* in_sizes, int n_in,
                              void* d_out, int out_size, void* d_ws, size_t ws_size,
                              hipStream_t stream) {
    const float* x    = (const float*)d_in[0];
    const int*   eidx = (const int*)d_in[1];
    const int*   batch= (const int*)d_in[2];
    const float* W0 = (const float*)d_in[3];  const float* b0 = (const float*)d_in[4];
    const float* W1 = (const float*)d_in[5];  const float* b1 = (const float*)d_in[6];
    const float* W2 = (const float*)d_in[7];  const float* b2 = (const float*)d_in[8];
    const float* Wc1= (const float*)d_in[9];  const float* bc1= (const float*)d_in[10];
    const float* Wc2= (const float*)d_in[11]; const float* bc2= (const float*)d_in[12];
    float* out = (float*)d_out;

    const int N   = in_sizes[2];       // 50000
    const int E   = in_sizes[1] / 2;   // 500000
    const int DIN = in_sizes[0] / N;   // 128
    const int DH  = in_sizes[4];       // 256
    const int* src = eidx;
    const int* dst = eidx + E;

    // workspace carve (256B aligned)
    char* p = (char*)d_ws;
    auto alloc = [&](size_t bytes) {
        char* r = p;
        p += (bytes + 255) & ~(size_t)255;
        return (void*)r;
    };
    float* buf1  = (float*)alloc((size_t)N * DH * 4);
    float* buf2  = (float*)alloc((size_t)N * DH * 4);
    int*   deg   = (int*)alloc((size_t)N * 4);
    float* dinv  = (float*)alloc((size_t)N * 4);
    int*   part  = (int*)alloc((size_t)N * 4);
    int*   bsum  = (int*)alloc(256 * 4);
    int*   rowptr= (int*)alloc((size_t)(N + 1) * 4);
    int*   cursor= (int*)alloc((size_t)N * 4);
    int*   col   = (int*)alloc((size_t)E * 4);
    float* nrm   = (float*)alloc((size_t)E * 4);
    int*   gstart= (int*)alloc(65 * 4);
    float* ppool = (float*)alloc(64 * (size_t)POOL_S * DH * 4);
    float* gpool = (float*)alloc(64 * (size_t)DH * 4);

    hipMemsetAsync(deg, 0, (size_t)N * 4, stream);

    const int nb = (N + 255) / 256;
    k_deg <<<(E + 255) / 256, 256, 0, stream>>>(dst, E, deg);
    k_dinv<<<nb, 256, 0, stream>>>(deg, N, dinv);
    k_scan1<<<nb, 256, 0, stream>>>(deg, N, part, bsum);
    k_scan2<<<1, 256, 0, stream>>>(bsum, nb);
    k_scan3<<<nb, 256, 0, stream>>>(part, bsum, N, E, rowptr, cursor);
    k_fill<<<(E + 255) / 256, 256, 0, stream>>>(src, dst, E, dinv, cursor, col, nrm);
    k_gbounds<<<1, 128, 0, stream>>>(batch, N, 64, gstart);

    dim3 gemmGrid(DH / BN, (N + BM - 1) / BM);
    const int aggBlocks = (N + 3) / 4;

    // layer 0: 128 -> 256
    k_gemm<<<gemmGrid, 256, 0, stream>>>(x, W0, buf1, N, DIN, DH);
    k_agg <<<aggBlocks, 256, 0, stream>>>(buf1, rowptr, col, nrm, dinv, b0, buf2, N);
    // layer 1: 256 -> 256
    k_gemm<<<gemmGrid, 256, 0, stream>>>(buf2, W1, buf1, N, DH, DH);
    k_agg <<<aggBlocks, 256, 0, stream>>>(buf1, rowptr, col, nrm, dinv, b1, buf2, N);
    // layer 2: 256 -> 256
    k_gemm<<<gemmGrid, 256, 0, stream>>>(buf2, W2, buf1, N, DH, DH);
    k_agg <<<aggBlocks, 256, 0, stream>>>(buf1, rowptr, col, nrm, dinv, b2, buf2, N);

    // pool + head
    dim3 poolGrid(64, POOL_S);
    k_pool1<<<poolGrid, 256, 0, stream>>>(buf2, gstart, ppool);
    k_pool2<<<64, 256, 0, stream>>>(ppool, gstart, gpool);
    k_cls <<<64, 256, 0, stream>>>(gpool, Wc1, bc1, Wc2, bc2, out);
}